// Round 1
// baseline (693.880 us; speedup 1.0000x reference)
//
#include <hip/hip_runtime.h>

#define CHUNK 8192           // edges per block in coarse pass
#define BMAX 512             // max coarse buckets (N/256 <= 512)

typedef __attribute__((address_space(3))) unsigned int lds_u32;
typedef const __attribute__((address_space(1))) unsigned int glb_u32;

// async 16B global -> LDS (global_load_lds_dwordx4). HW dest = wave-uniform
// base + lane*16, which our flat slot layout satisfies exactly.
__device__ __forceinline__ void gload16(const float* g, float* l) {
    __builtin_amdgcn_global_load_lds((glb_u32*)g, (lds_u32*)l, 16, 0, 0);
}

// ---------------- coarse bucket histogram ----------------

__global__ __launch_bounds__(256) void k_coarse_hist(const int* __restrict__ dst, int E,
                                                     int* __restrict__ bc,
                                                     int* __restrict__ blockBase, int B) {
    __shared__ int cnt[BMAX];
    int t = threadIdx.x;
    cnt[t] = 0; cnt[t + 256] = 0;
    __syncthreads();
    int e0 = blockIdx.x * CHUNK;
#pragma unroll
    for (int it = 0; it < CHUNK / 256; ++it) {
        int e = e0 + it * 256 + t;
        if (e < E) atomicAdd(&cnt[dst[e] >> 8], 1);
    }
    __syncthreads();
    for (int b = t; b < B; b += 256) {
        int c = cnt[b];
        if (c > 0) blockBase[(size_t)blockIdx.x * B + b] = atomicAdd(&bc[b], c);
    }
}

// single block, 512 threads; exclusive scan in place (n <= 512)
__global__ void k_scan_bsums(int* bsums, int nb) {
    __shared__ int s[2][512];
    int t = threadIdx.x;
    int v = (t < nb) ? bsums[t] : 0;
    int p = 0;
    s[0][t] = v;
    __syncthreads();
    for (int off = 1; off < 512; off <<= 1) {
        s[p ^ 1][t] = s[p][t] + ((t >= off) ? s[p][t - off] : 0);
        p ^= 1;
        __syncthreads();
    }
    if (t < nb) bsums[t] = s[p][t] - v;  // exclusive
}

// ---------------- coarse scatter ----------------

__global__ __launch_bounds__(256) void k_coarse_scatter(const int* __restrict__ src,
                                                        const int* __restrict__ dst, int E,
                                                        const int* __restrict__ bucketBase,
                                                        const int* __restrict__ blockBase, int B,
                                                        unsigned int* __restrict__ ebuf) {
    __shared__ int run[BMAX];
    int t = threadIdx.x;
    run[t] = 0; run[t + 256] = 0;
    __syncthreads();
    int e0 = blockIdx.x * CHUNK;
#pragma unroll
    for (int it = 0; it < CHUNK / 256; ++it) {
        int e = e0 + it * 256 + t;
        if (e < E) {
            int d = dst[e];
            int b = d >> 8;
            int rank = atomicAdd(&run[b], 1);
            int pos = bucketBase[b] + blockBase[(size_t)blockIdx.x * B + b] + rank;
            ebuf[pos] = ((unsigned int)(d & 255) << 24) | (unsigned int)src[e];
        }
    }
}

// ---------------- per-node degree histogram + dinv from bucketed edges ----------------

__global__ __launch_bounds__(256) void k_bucket_hist(const unsigned int* __restrict__ ebuf,
                                                     const int* __restrict__ bucketBase,
                                                     int E, int N, int B,
                                                     int* __restrict__ hist,
                                                     float* __restrict__ dinv) {
    __shared__ int cnt[256];
    int t = threadIdx.x;
    int b = blockIdx.x;
    cnt[t] = 0;
    __syncthreads();
    int e0 = bucketBase[b];
    int e1 = (b + 1 < B) ? bucketBase[b + 1] : E;
    for (int e = e0 + t; e < e1; e += 256) atomicAdd(&cnt[ebuf[e] >> 24], 1);
    __syncthreads();
    int node = b * 256 + t;
    if (node < N) {
        hist[node] = cnt[t];
        dinv[node] = rsqrtf((float)(cnt[t] + 1));  // +1 self-loop
    }
}

// ---------------- fine scatter (fused rowStart scan): bucket -> CSR ----------------

__global__ __launch_bounds__(256) void k_fine_scatter(const unsigned int* __restrict__ ebuf,
                                                      const int* __restrict__ bucketBase,
                                                      const int* __restrict__ hist,
                                                      int E, int N, int B,
                                                      int* __restrict__ rowStart,
                                                      int* __restrict__ csr_src) {
    __shared__ int s[2][256];
    __shared__ int cnt[256];
    int t = threadIdx.x;
    int b = blockIdx.x;
    int node = b * 256 + t;
    int v = (node < N) ? hist[node] : 0;
    int p = 0;
    s[0][t] = v;
    __syncthreads();
    for (int off = 1; off < 256; off <<= 1) {
        s[p ^ 1][t] = s[p][t] + ((t >= off) ? s[p][t - off] : 0);
        p ^= 1;
        __syncthreads();
    }
    int rs = bucketBase[b] + s[p][t] - v;
    if (node < N) rowStart[node] = rs;
    cnt[t] = rs;
    __syncthreads();
    int e0 = bucketBase[b];
    int e1 = (b + 1 < B) ? bucketBase[b + 1] : E;
    for (int e = e0 + t; e < e1; e += 256) {
        unsigned int w = ebuf[e];
        int pos = atomicAdd(&cnt[w >> 24], 1);
        csr_src[pos] = (int)(w & 0xFFFFFFu);
    }
}

// ---------------- GEMM1: h1 += (X[:, ksplit] @ W1[ksplit, :]) * dinv[row] ----------------
// Restructured for occupancy: 128 rows/block x K-split=2 -> grid 1564 (was 391),
// LDS 2x16KB (was 2x32KB) -> 5 blocks/CU resident (was 2, with only 1.53 avail).
// 256 threads: thread owns (row = t&127, c-half = t>>7), 8 accumulators.
// Same conflict-free layout: rows stay 32 floats (128B), slot g^(r&7) XOR swizzle
// keeps the flat DMA layout conflict-free for the stride-128B ds_read_b128.
// Partial K-sums combined via HW fp32 atomics into zeroed h1.

__global__ __launch_bounds__(256) void k_gemm1(const float* __restrict__ x,
                                               const float* __restrict__ W1,
                                               const float* __restrict__ dinv,
                                               int N, float* __restrict__ h1) {
    __shared__ float xs[2][128 * 32];  // 2 x 16 KB
    const int t = threadIdx.x;
    const int rb = blockIdx.x >> 1;        // row-block
    const int kb = (blockIdx.x & 1) * 256; // k-split base
    const int R0 = rb * 128;
    const int tk = t & 7;
    const int chalf = __builtin_amdgcn_readfirstlane(t >> 7);  // wave-uniform c-half

    // per-lane global base (chunk 0) and LDS slot for each of 4 issues
    const float* gbase[4];
#pragma unroll
    for (int it = 0; it < 4; ++it) {
        int r = it * 32 + (t >> 3);        // row handled by this lane-slot
        int j4 = tk ^ (r & 7);             // swizzled k-group stored here
        int row = R0 + r;
        if (row >= N) row = N - 1;         // clamp: garbage lands in never-stored accs
        gbase[it] = x + (size_t)row * 512 + kb + j4 * 4;
    }

    float acc[8];
#pragma unroll
    for (int c = 0; c < 8; ++c) acc[c] = 0.0f;

    // prologue: chunk 0 -> buf 0
#pragma unroll
    for (int it = 0; it < 4; ++it)
        gload16(gbase[it], &xs[0][(it * 256 + t) * 4]);
    __syncthreads();  // vmcnt(0) drain + barrier

    int p = 0;
    for (int ch = 0; ch < 8; ++ch) {
        if (ch + 1 < 8) {
#pragma unroll
            for (int it = 0; it < 4; ++it)
                gload16(gbase[it] + (ch + 1) * 32, &xs[p ^ 1][(it * 256 + t) * 4]);
        }
        // compute chunk ch from buf p; j4 = logical k-group (W1 idx wave-uniform)
        const float* xr = &xs[p][(t & 127) * 32];
#pragma unroll
        for (int j4 = 0; j4 < 8; ++j4) {
            float4 xv = *(const float4*)(xr + ((j4 ^ tk) << 2));
            float xe[4] = {xv.x, xv.y, xv.z, xv.w};
            int k = kb + ch * 32 + j4 * 4;
#pragma unroll
            for (int d = 0; d < 4; ++d) {
                const float* w = W1 + (k + d) * 16 + chalf * 8;  // wave-uniform -> s_load
#pragma unroll
                for (int c = 0; c < 8; ++c) acc[c] = fmaf(xe[d], w[c], acc[c]);
            }
        }
        __syncthreads();  // prefetch had FMA cover before this drain
        p ^= 1;
    }

    int row = R0 + (t & 127);
    if (row < N) {
        float di = dinv[row];
        float* o = h1 + (size_t)row * 16 + chalf * 8;
#pragma unroll
        for (int c = 0; c < 8; ++c) unsafeAtomicAdd(&o[c], acc[c] * di);
    }
}

// ---------------- Aggregation layer 1: relu1 = relu(di * sum(h1') + b1) ----------------

__global__ void k_gather1(const float* __restrict__ h1, const int* __restrict__ csr_src,
                          const int* __restrict__ rowStart, const int* __restrict__ hist,
                          const float* __restrict__ dinv, const float* __restrict__ b1,
                          int N, float* __restrict__ relu1) {
    int g = blockIdx.x * blockDim.x + threadIdx.x;
    int i = g >> 4, c = g & 15;
    if (i >= N) return;
    float ssum = h1[(size_t)i * 16 + c];  // self-loop (already * dinv[i])
    int e0 = rowStart[i], e1 = e0 + hist[i];
    for (int e = e0; e < e1; ++e) {
        int s = csr_src[e];
        ssum += h1[(size_t)s * 16 + c];
    }
    float v = fmaf(dinv[i], ssum, b1[c]);
    relu1[(size_t)i * 16 + c] = fmaxf(v, 0.0f);
}

// ---------------- h2 = (relu1 @ W2) * dinv[i]  (W2 [16,7]) ----------------

__global__ void k_h2(const float* __restrict__ relu1, const float* __restrict__ W2,
                     const float* __restrict__ dinv, int N, float* __restrict__ h2) {
    int i = blockIdx.x * blockDim.x + threadIdx.x;
    if (i >= N) return;
    float r[16];
#pragma unroll
    for (int q = 0; q < 4; ++q) {
        float4 v = *(const float4*)(relu1 + (size_t)i * 16 + q * 4);
        r[q * 4 + 0] = v.x; r[q * 4 + 1] = v.y; r[q * 4 + 2] = v.z; r[q * 4 + 3] = v.w;
    }
    float di = dinv[i];
#pragma unroll
    for (int c2 = 0; c2 < 7; ++c2) {
        float a = 0.0f;
#pragma unroll
        for (int c = 0; c < 16; ++c) a = fmaf(r[c], W2[c * 7 + c2], a);
        h2[(size_t)i * 7 + c2] = a * di;
    }
}

// ---------------- Aggregation layer 2: out = di * sum(h2') + b2 ----------------

__global__ void k_gather2(const float* __restrict__ h2, const int* __restrict__ csr_src,
                          const int* __restrict__ rowStart, const int* __restrict__ hist,
                          const float* __restrict__ dinv, const float* __restrict__ b2,
                          int N, float* __restrict__ out) {
    int g = blockIdx.x * blockDim.x + threadIdx.x;
    int i = g >> 3, c = g & 7;
    if (i >= N || c >= 7) return;
    float ssum = h2[(size_t)i * 7 + c];
    int e0 = rowStart[i], e1 = e0 + hist[i];
    for (int e = e0; e < e1; ++e) {
        int s = csr_src[e];
        ssum += h2[(size_t)s * 7 + c];
    }
    out[(size_t)i * 7 + c] = fmaf(dinv[i], ssum, b2[c]);
}

// ---------------- launch ----------------

extern "C" void kernel_launch(void* const* d_in, const int* in_sizes, int n_in,
                              void* d_out, int out_size, void* d_ws, size_t ws_size,
                              hipStream_t stream) {
    const float* x  = (const float*)d_in[0];
    const int*   ei = (const int*)d_in[1];
    const float* W1 = (const float*)d_in[2];
    const float* b1 = (const float*)d_in[3];
    const float* W2 = (const float*)d_in[4];
    const float* b2 = (const float*)d_in[5];
    float* out = (float*)d_out;

    const int N = in_sizes[0] / 512;
    const int E = in_sizes[1] / 2;
    const int* src = ei;       // edge_index[0]
    const int* dst = ei + E;   // edge_index[1]

    const int nb  = (N + 255) / 256;           // 391 node blocks == coarse buckets
    const int B   = nb;
    const int nbA = (E + CHUNK - 1) / CHUNK;   // 391 coarse blocks
    const int nb2 = (N + 127) / 128;           // 782 gemm row-blocks

    char* ws = (char*)d_ws;
    auto alloc = [&](size_t bytes) {
        char* p = ws;
        ws += (bytes + 511) & ~(size_t)511;
        return p;
    };
    // persistent region
    int*   hist      = (int*)alloc((size_t)N * 4);
    float* dinv      = (float*)alloc((size_t)N * 4);
    int*   rowStart  = (int*)alloc((size_t)N * 4);
    int*   bc        = (int*)alloc((size_t)(B + 1) * 4);
    int*   blockBase = (int*)alloc((size_t)nbA * B * 4);
    int*   csr_src   = (int*)alloc((size_t)E * 4);
    // overlapped region: ebuf (dead after fine_scatter) unions with h1/relu1/h2
    size_t featBytes = (size_t)N * 16 * 4 * 2 + (size_t)N * 7 * 4;
    size_t ebufBytes = (size_t)E * 4;
    char* regB = alloc(featBytes > ebufBytes ? featBytes : ebufBytes);
    unsigned int* ebuf = (unsigned int*)regB;
    float* h1    = (float*)regB;
    float* relu1 = h1 + (size_t)N * 16;
    float* h2    = relu1 + (size_t)N * 16;

    hipMemsetAsync(bc, 0, (size_t)B * 4, stream);
    k_coarse_hist<<<nbA, 256, 0, stream>>>(dst, E, bc, blockBase, B);
    k_scan_bsums<<<1, 512, 0, stream>>>(bc, B);                       // bc -> bucketBase
    k_coarse_scatter<<<nbA, 256, 0, stream>>>(src, dst, E, bc, blockBase, B, ebuf);
    k_bucket_hist<<<B, 256, 0, stream>>>(ebuf, bc, E, N, B, hist, dinv);
    k_fine_scatter<<<B, 256, 0, stream>>>(ebuf, bc, hist, E, N, B, rowStart, csr_src);
    hipMemsetAsync(h1, 0, (size_t)N * 16 * 4, stream);                // ebuf dead now
    k_gemm1<<<nb2 * 2, 256, 0, stream>>>(x, W1, dinv, N, h1);
    k_gather1<<<(N * 16 + 255) / 256, 256, 0, stream>>>(h1, csr_src, rowStart, hist, dinv, b1, N, relu1);
    k_h2<<<nb, 256, 0, stream>>>(relu1, W2, dinv, N, h2);
    k_gather2<<<(N * 8 + 255) / 256, 256, 0, stream>>>(h2, csr_src, rowStart, hist, dinv, b2, N, out);
}

// Round 2
// 604.448 us; speedup vs baseline: 1.1480x; 1.1480x over previous
//
#include <hip/hip_runtime.h>

#define CHUNK 8192           // edges per block in coarse pass
#define BMAX 512             // max coarse buckets (N/256 <= 512)

typedef __attribute__((address_space(3))) unsigned int lds_u32;
typedef const __attribute__((address_space(1))) unsigned int glb_u32;

// async 16B global -> LDS (global_load_lds_dwordx4). HW dest = wave-uniform
// base + lane*16, which our flat slot layout satisfies exactly.
__device__ __forceinline__ void gload16(const float* g, float* l) {
    __builtin_amdgcn_global_load_lds((glb_u32*)g, (lds_u32*)l, 16, 0, 0);
}

// ---------------- coarse bucket histogram ----------------

__global__ __launch_bounds__(256) void k_coarse_hist(const int* __restrict__ dst, int E,
                                                     int* __restrict__ bc,
                                                     int* __restrict__ blockBase, int B) {
    __shared__ int cnt[BMAX];
    int t = threadIdx.x;
    cnt[t] = 0; cnt[t + 256] = 0;
    __syncthreads();
    int e0 = blockIdx.x * CHUNK;
#pragma unroll
    for (int it = 0; it < CHUNK / 256; ++it) {
        int e = e0 + it * 256 + t;
        if (e < E) atomicAdd(&cnt[dst[e] >> 8], 1);
    }
    __syncthreads();
    for (int b = t; b < B; b += 256) {
        int c = cnt[b];
        if (c > 0) blockBase[(size_t)blockIdx.x * B + b] = atomicAdd(&bc[b], c);
    }
}

// single block, 512 threads; exclusive scan in place (n <= 512)
__global__ void k_scan_bsums(int* bsums, int nb) {
    __shared__ int s[2][512];
    int t = threadIdx.x;
    int v = (t < nb) ? bsums[t] : 0;
    int p = 0;
    s[0][t] = v;
    __syncthreads();
    for (int off = 1; off < 512; off <<= 1) {
        s[p ^ 1][t] = s[p][t] + ((t >= off) ? s[p][t - off] : 0);
        p ^= 1;
        __syncthreads();
    }
    if (t < nb) bsums[t] = s[p][t] - v;  // exclusive
}

// ---------------- coarse scatter ----------------

__global__ __launch_bounds__(256) void k_coarse_scatter(const int* __restrict__ src,
                                                        const int* __restrict__ dst, int E,
                                                        const int* __restrict__ bucketBase,
                                                        const int* __restrict__ blockBase, int B,
                                                        unsigned int* __restrict__ ebuf) {
    __shared__ int run[BMAX];
    int t = threadIdx.x;
    run[t] = 0; run[t + 256] = 0;
    __syncthreads();
    int e0 = blockIdx.x * CHUNK;
#pragma unroll
    for (int it = 0; it < CHUNK / 256; ++it) {
        int e = e0 + it * 256 + t;
        if (e < E) {
            int d = dst[e];
            int b = d >> 8;
            int rank = atomicAdd(&run[b], 1);
            int pos = bucketBase[b] + blockBase[(size_t)blockIdx.x * B + b] + rank;
            ebuf[pos] = ((unsigned int)(d & 255) << 24) | (unsigned int)src[e];
        }
    }
}

// ---------------- per-node degree histogram + dinv from bucketed edges ----------------

__global__ __launch_bounds__(256) void k_bucket_hist(const unsigned int* __restrict__ ebuf,
                                                     const int* __restrict__ bucketBase,
                                                     int E, int N, int B,
                                                     int* __restrict__ hist,
                                                     float* __restrict__ dinv) {
    __shared__ int cnt[256];
    int t = threadIdx.x;
    int b = blockIdx.x;
    cnt[t] = 0;
    __syncthreads();
    int e0 = bucketBase[b];
    int e1 = (b + 1 < B) ? bucketBase[b + 1] : E;
    for (int e = e0 + t; e < e1; e += 256) atomicAdd(&cnt[ebuf[e] >> 24], 1);
    __syncthreads();
    int node = b * 256 + t;
    if (node < N) {
        hist[node] = cnt[t];
        dinv[node] = rsqrtf((float)(cnt[t] + 1));  // +1 self-loop
    }
}

// ---------------- fine scatter (fused rowStart scan): bucket -> CSR ----------------

__global__ __launch_bounds__(256) void k_fine_scatter(const unsigned int* __restrict__ ebuf,
                                                      const int* __restrict__ bucketBase,
                                                      const int* __restrict__ hist,
                                                      int E, int N, int B,
                                                      int* __restrict__ rowStart,
                                                      int* __restrict__ csr_src) {
    __shared__ int s[2][256];
    __shared__ int cnt[256];
    int t = threadIdx.x;
    int b = blockIdx.x;
    int node = b * 256 + t;
    int v = (node < N) ? hist[node] : 0;
    int p = 0;
    s[0][t] = v;
    __syncthreads();
    for (int off = 1; off < 256; off <<= 1) {
        s[p ^ 1][t] = s[p][t] + ((t >= off) ? s[p][t - off] : 0);
        p ^= 1;
        __syncthreads();
    }
    int rs = bucketBase[b] + s[p][t] - v;
    if (node < N) rowStart[node] = rs;
    cnt[t] = rs;
    __syncthreads();
    int e0 = bucketBase[b];
    int e1 = (b + 1 < B) ? bucketBase[b + 1] : E;
    for (int e = e0 + t; e < e1; e += 256) {
        unsigned int w = ebuf[e];
        int pos = atomicAdd(&cnt[w >> 24], 1);
        csr_src[pos] = (int)(w & 0xFFFFFFu);
    }
}

// ---------------- GEMM1: h1 = (X @ W1) * dinv[row] ----------------
// Row-streaming restructure (R1 post-mortem: k-chunked staging read X in
// 128B strips at 2KB stride -> DRAM page thrash capped HBM at ~850 GB/s).
// Each block stages 64 COMPLETE rows = one contiguous 128KB region of X
// (m201-proven LDS size), so the HBM stream is fully sequential.
// Compute mapping: row = lane (64 rows), k-quarter = wave (wave-uniform k
// -> W1 via s_load broadcast, 16 accs/thread), then a 16KB LDS reduction
// over the 4 k-quarters (no atomics). XOR swizzle on 16B groups (low 3
// bits, within 128B blocks) spreads the stride-2KB ds_read_b128 across
// banks; source is pre-swizzled per-lane so the DMA dest stays linear
// (both-sides involution, rule 21) and global coalescing is preserved.

__global__ __launch_bounds__(256) void k_gemm1(const float* __restrict__ x,
                                               const float* __restrict__ W1,
                                               const float* __restrict__ dinv,
                                               int N, float* __restrict__ h1) {
    __shared__ float xs[64 * 512];  // 128 KB: 64 full rows, swizzled 16B groups
    const int t = threadIdx.x;
    const int lane = t & 63;
    const int w = __builtin_amdgcn_readfirstlane(t >> 6);  // wave 0..3
    const int R0 = blockIdx.x * 64;

    // ---- stage: wave w DMAs rows [w*16, w*16+16), two 1KB halves each ----
#pragma unroll
    for (int u = 0; u < 32; ++u) {
        int r = w * 16 + (u >> 1);
        int h = u & 1;
        int row = R0 + r;
        if (row >= N) row = N - 1;  // clamp: tail rows discarded at store
        const float* src = x + (size_t)row * 512 + h * 256 + ((lane ^ (r & 7)) << 2);
        gload16(src, &xs[r * 512 + h * 256]);
    }
    __syncthreads();  // vmcnt(0) drain + barrier

    // ---- compute: thread = (row r = lane, k-quarter = wave) ----
    float acc[16];
#pragma unroll
    for (int c = 0; c < 16; ++c) acc[c] = 0.0f;
    const int sw = lane & 7;
#pragma unroll 4
    for (int k4 = 0; k4 < 32; ++k4) {
        int g = w * 32 + k4;  // logical 16B-group index within row (0..127)
        const float4 xv = *(const float4*)&xs[lane * 512 + ((g ^ sw) << 2)];
        float xe[4] = {xv.x, xv.y, xv.z, xv.w};
        int k = g << 2;
#pragma unroll
        for (int d = 0; d < 4; ++d) {
            const float* wp = W1 + (k + d) * 16;  // wave-uniform -> s_load
#pragma unroll
            for (int c = 0; c < 16; ++c) acc[c] = fmaf(xe[d], wp[c], acc[c]);
        }
    }
    __syncthreads();

    // ---- k-quarter reduction via LDS (reuse xs: 4*64*16 floats = 16KB) ----
    float* red = xs;
#pragma unroll
    for (int cg = 0; cg < 4; ++cg)
        *(float4*)&red[(w * 64 + lane) * 16 + cg * 4] =
            make_float4(acc[cg * 4], acc[cg * 4 + 1], acc[cg * 4 + 2], acc[cg * 4 + 3]);
    __syncthreads();

    int r = t >> 2, cg = (t & 3) * 4;
    int row = R0 + r;
    if (row < N) {
        float4 s0 = *(float4*)&red[(0 * 64 + r) * 16 + cg];
        float4 s1 = *(float4*)&red[(1 * 64 + r) * 16 + cg];
        float4 s2 = *(float4*)&red[(2 * 64 + r) * 16 + cg];
        float4 s3 = *(float4*)&red[(3 * 64 + r) * 16 + cg];
        float di = dinv[row];
        float4 o;
        o.x = (s0.x + s1.x + s2.x + s3.x) * di;
        o.y = (s0.y + s1.y + s2.y + s3.y) * di;
        o.z = (s0.z + s1.z + s2.z + s3.z) * di;
        o.w = (s0.w + s1.w + s2.w + s3.w) * di;
        *(float4*)(h1 + (size_t)row * 16 + cg) = o;
    }
}

// ---------------- Aggregation layer 1: relu1 = relu(di * sum(h1') + b1) ----------------

__global__ void k_gather1(const float* __restrict__ h1, const int* __restrict__ csr_src,
                          const int* __restrict__ rowStart, const int* __restrict__ hist,
                          const float* __restrict__ dinv, const float* __restrict__ b1,
                          int N, float* __restrict__ relu1) {
    int g = blockIdx.x * blockDim.x + threadIdx.x;
    int i = g >> 4, c = g & 15;
    if (i >= N) return;
    float ssum = h1[(size_t)i * 16 + c];  // self-loop (already * dinv[i])
    int e0 = rowStart[i], e1 = e0 + hist[i];
    for (int e = e0; e < e1; ++e) {
        int s = csr_src[e];
        ssum += h1[(size_t)s * 16 + c];
    }
    float v = fmaf(dinv[i], ssum, b1[c]);
    relu1[(size_t)i * 16 + c] = fmaxf(v, 0.0f);
}

// ---------------- h2 = (relu1 @ W2) * dinv[i]  (W2 [16,7]) ----------------

__global__ void k_h2(const float* __restrict__ relu1, const float* __restrict__ W2,
                     const float* __restrict__ dinv, int N, float* __restrict__ h2) {
    int i = blockIdx.x * blockDim.x + threadIdx.x;
    if (i >= N) return;
    float r[16];
#pragma unroll
    for (int q = 0; q < 4; ++q) {
        float4 v = *(const float4*)(relu1 + (size_t)i * 16 + q * 4);
        r[q * 4 + 0] = v.x; r[q * 4 + 1] = v.y; r[q * 4 + 2] = v.z; r[q * 4 + 3] = v.w;
    }
    float di = dinv[i];
#pragma unroll
    for (int c2 = 0; c2 < 7; ++c2) {
        float a = 0.0f;
#pragma unroll
        for (int c = 0; c < 16; ++c) a = fmaf(r[c], W2[c * 7 + c2], a);
        h2[(size_t)i * 7 + c2] = a * di;
    }
}

// ---------------- Aggregation layer 2: out = di * sum(h2') + b2 ----------------

__global__ void k_gather2(const float* __restrict__ h2, const int* __restrict__ csr_src,
                          const int* __restrict__ rowStart, const int* __restrict__ hist,
                          const float* __restrict__ dinv, const float* __restrict__ b2,
                          int N, float* __restrict__ out) {
    int g = blockIdx.x * blockDim.x + threadIdx.x;
    int i = g >> 3, c = g & 7;
    if (i >= N || c >= 7) return;
    float ssum = h2[(size_t)i * 7 + c];
    int e0 = rowStart[i], e1 = e0 + hist[i];
    for (int e = e0; e < e1; ++e) {
        int s = csr_src[e];
        ssum += h2[(size_t)s * 7 + c];
    }
    out[(size_t)i * 7 + c] = fmaf(dinv[i], ssum, b2[c]);
}

// ---------------- launch ----------------

extern "C" void kernel_launch(void* const* d_in, const int* in_sizes, int n_in,
                              void* d_out, int out_size, void* d_ws, size_t ws_size,
                              hipStream_t stream) {
    const float* x  = (const float*)d_in[0];
    const int*   ei = (const int*)d_in[1];
    const float* W1 = (const float*)d_in[2];
    const float* b1 = (const float*)d_in[3];
    const float* W2 = (const float*)d_in[4];
    const float* b2 = (const float*)d_in[5];
    float* out = (float*)d_out;

    const int N = in_sizes[0] / 512;
    const int E = in_sizes[1] / 2;
    const int* src = ei;       // edge_index[0]
    const int* dst = ei + E;   // edge_index[1]

    const int nb  = (N + 255) / 256;           // 391 node blocks == coarse buckets
    const int B   = nb;
    const int nbA = (E + CHUNK - 1) / CHUNK;   // 391 coarse blocks
    const int nb64 = (N + 63) / 64;            // 1563 gemm row-blocks (64 rows each)

    char* ws = (char*)d_ws;
    auto alloc = [&](size_t bytes) {
        char* p = ws;
        ws += (bytes + 511) & ~(size_t)511;
        return p;
    };
    // persistent region
    int*   hist      = (int*)alloc((size_t)N * 4);
    float* dinv      = (float*)alloc((size_t)N * 4);
    int*   rowStart  = (int*)alloc((size_t)N * 4);
    int*   bc        = (int*)alloc((size_t)(B + 1) * 4);
    int*   blockBase = (int*)alloc((size_t)nbA * B * 4);
    int*   csr_src   = (int*)alloc((size_t)E * 4);
    // overlapped region: ebuf (dead after fine_scatter) unions with h1/relu1/h2
    size_t featBytes = (size_t)N * 16 * 4 * 2 + (size_t)N * 7 * 4;
    size_t ebufBytes = (size_t)E * 4;
    char* regB = alloc(featBytes > ebufBytes ? featBytes : ebufBytes);
    unsigned int* ebuf = (unsigned int*)regB;
    float* h1    = (float*)regB;
    float* relu1 = h1 + (size_t)N * 16;
    float* h2    = relu1 + (size_t)N * 16;

    hipMemsetAsync(bc, 0, (size_t)B * 4, stream);
    k_coarse_hist<<<nbA, 256, 0, stream>>>(dst, E, bc, blockBase, B);
    k_scan_bsums<<<1, 512, 0, stream>>>(bc, B);                       // bc -> bucketBase
    k_coarse_scatter<<<nbA, 256, 0, stream>>>(src, dst, E, bc, blockBase, B, ebuf);
    k_bucket_hist<<<B, 256, 0, stream>>>(ebuf, bc, E, N, B, hist, dinv);
    k_fine_scatter<<<B, 256, 0, stream>>>(ebuf, bc, hist, E, N, B, rowStart, csr_src);
    k_gemm1<<<nb64, 256, 0, stream>>>(x, W1, dinv, N, h1);
    k_gather1<<<(N * 16 + 255) / 256, 256, 0, stream>>>(h1, csr_src, rowStart, hist, dinv, b1, N, relu1);
    k_h2<<<nb, 256, 0, stream>>>(relu1, W2, dinv, N, h2);
    k_gather2<<<(N * 8 + 255) / 256, 256, 0, stream>>>(h2, csr_src, rowStart, hist, dinv, b2, N, out);
}

// Round 3
// 558.728 us; speedup vs baseline: 1.2419x; 1.0818x over previous
//
#include <hip/hip_runtime.h>

#define CHUNK 8192           // edges per block in coarse pass
#define BMAX 512             // max coarse buckets (N/256 <= 512)

typedef __attribute__((address_space(3))) unsigned int lds_u32;
typedef const __attribute__((address_space(1))) unsigned int glb_u32;

// async 16B global -> LDS (global_load_lds_dwordx4). HW dest = wave-uniform
// base + lane*16, which our flat slot layout satisfies exactly.
__device__ __forceinline__ void gload16(const float* g, float* l) {
    __builtin_amdgcn_global_load_lds((glb_u32*)g, (lds_u32*)l, 16, 0, 0);
}

// ---------------- coarse bucket histogram ----------------

__global__ __launch_bounds__(256) void k_coarse_hist(const int* __restrict__ dst, int E,
                                                     int* __restrict__ bc,
                                                     int* __restrict__ blockBase, int B) {
    __shared__ int cnt[BMAX];
    int t = threadIdx.x;
    cnt[t] = 0; cnt[t + 256] = 0;
    __syncthreads();
    int e0 = blockIdx.x * CHUNK;
#pragma unroll
    for (int it = 0; it < CHUNK / 256; ++it) {
        int e = e0 + it * 256 + t;
        if (e < E) atomicAdd(&cnt[dst[e] >> 8], 1);
    }
    __syncthreads();
    for (int b = t; b < B; b += 256) {
        int c = cnt[b];
        if (c > 0) blockBase[(size_t)blockIdx.x * B + b] = atomicAdd(&bc[b], c);
    }
}

// single block, 512 threads; exclusive scan in place (n <= 512)
__global__ void k_scan_bsums(int* bsums, int nb) {
    __shared__ int s[2][512];
    int t = threadIdx.x;
    int v = (t < nb) ? bsums[t] : 0;
    int p = 0;
    s[0][t] = v;
    __syncthreads();
    for (int off = 1; off < 512; off <<= 1) {
        s[p ^ 1][t] = s[p][t] + ((t >= off) ? s[p][t - off] : 0);
        p ^= 1;
        __syncthreads();
    }
    if (t < nb) bsums[t] = s[p][t] - v;  // exclusive
}

// ---------------- coarse scatter ----------------

__global__ __launch_bounds__(256) void k_coarse_scatter(const int* __restrict__ src,
                                                        const int* __restrict__ dst, int E,
                                                        const int* __restrict__ bucketBase,
                                                        const int* __restrict__ blockBase, int B,
                                                        unsigned int* __restrict__ ebuf) {
    __shared__ int run[BMAX];
    int t = threadIdx.x;
    run[t] = 0; run[t + 256] = 0;
    __syncthreads();
    int e0 = blockIdx.x * CHUNK;
#pragma unroll
    for (int it = 0; it < CHUNK / 256; ++it) {
        int e = e0 + it * 256 + t;
        if (e < E) {
            int d = dst[e];
            int b = d >> 8;
            int rank = atomicAdd(&run[b], 1);
            int pos = bucketBase[b] + blockBase[(size_t)blockIdx.x * B + b] + rank;
            ebuf[pos] = ((unsigned int)(d & 255) << 24) | (unsigned int)src[e];
        }
    }
}

// ---------------- per-node degree histogram + dinv from bucketed edges ----------------

__global__ __launch_bounds__(256) void k_bucket_hist(const unsigned int* __restrict__ ebuf,
                                                     const int* __restrict__ bucketBase,
                                                     int E, int N, int B,
                                                     int* __restrict__ hist,
                                                     float* __restrict__ dinv) {
    __shared__ int cnt[256];
    int t = threadIdx.x;
    int b = blockIdx.x;
    cnt[t] = 0;
    __syncthreads();
    int e0 = bucketBase[b];
    int e1 = (b + 1 < B) ? bucketBase[b + 1] : E;
    for (int e = e0 + t; e < e1; e += 256) atomicAdd(&cnt[ebuf[e] >> 24], 1);
    __syncthreads();
    int node = b * 256 + t;
    if (node < N) {
        hist[node] = cnt[t];
        dinv[node] = rsqrtf((float)(cnt[t] + 1));  // +1 self-loop
    }
}

// ---------------- fine scatter (fused rowStart scan): bucket -> CSR ----------------

__global__ __launch_bounds__(256) void k_fine_scatter(const unsigned int* __restrict__ ebuf,
                                                      const int* __restrict__ bucketBase,
                                                      const int* __restrict__ hist,
                                                      int E, int N, int B,
                                                      int* __restrict__ rowStart,
                                                      int* __restrict__ csr_src) {
    __shared__ int s[2][256];
    __shared__ int cnt[256];
    int t = threadIdx.x;
    int b = blockIdx.x;
    int node = b * 256 + t;
    int v = (node < N) ? hist[node] : 0;
    int p = 0;
    s[0][t] = v;
    __syncthreads();
    for (int off = 1; off < 256; off <<= 1) {
        s[p ^ 1][t] = s[p][t] + ((t >= off) ? s[p][t - off] : 0);
        p ^= 1;
        __syncthreads();
    }
    int rs = bucketBase[b] + s[p][t] - v;
    if (node < N) rowStart[node] = rs;
    cnt[t] = rs;
    __syncthreads();
    int e0 = bucketBase[b];
    int e1 = (b + 1 < B) ? bucketBase[b + 1] : E;
    for (int e = e0 + t; e < e1; e += 256) {
        unsigned int w = ebuf[e];
        int pos = atomicAdd(&cnt[w >> 24], 1);
        csr_src[pos] = (int)(w & 0xFFFFFFu);
    }
}

// ---------------- GEMM1: h1 = (X @ W1) * dinv[row] ----------------
// R2 post-mortem: per-CU fetch rate was invariant at ~2.6-3.2 B/cyc across
// all access patterns -- the limiter is per-CU concurrency/overlap, not the
// stream shape (m97 sustains ~22 B/cyc/CU through the same gload_lds path
// with 3-4 resident blocks at mixed phases). This version maximizes
// residency: 64 rows/block (grid 1563), 2x8KB double-buffered LDS, ~6
// resident blocks/CU, R0's proven issue(ch+1)/compute(ch) pipeline.
// Thread = (row = lane, col-quarter = wave): each thread owns the full K
// for 4 output cols -> no reduction, no atomics. W1 index wave-uniform
// (s_load broadcast). XOR swizzle slot g^(r&7) keeps the linear DMA dest
// (rule 21) and spreads the stride-128B ds_read_b128 across banks; per-wave
// j4 rotation spreads the 4 waves' concurrent reads.

__global__ __launch_bounds__(256, 6) void k_gemm1(const float* __restrict__ x,
                                                  const float* __restrict__ W1,
                                                  const float* __restrict__ dinv,
                                                  int N, float* __restrict__ h1) {
    __shared__ float xs[2][2048];  // 2 x 8 KB: 64 rows x 32 floats (one k-chunk)
    const int t = threadIdx.x;
    const int lane = t & 63;
    const int cq = __builtin_amdgcn_readfirstlane(t >> 6);  // wave 0..3 = col-quarter
    const int R0 = blockIdx.x * 64;

    // two DMA issues per wave per chunk; per-lane pre-swizzled source bases
    const float* gbase[2];
#pragma unroll
    for (int u = 0; u < 2; ++u) {
        int r = (cq * 2 + u) * 8 + (lane >> 3);   // LDS row this lane-slot fills
        int g = lane & 7;                         // 16B-slot within row
        int row = R0 + r;
        if (row >= N) row = N - 1;                // clamp: tail rows never stored
        gbase[u] = x + (size_t)row * 512 + ((g ^ (r & 7)) << 2);
    }

    float acc[4] = {0.f, 0.f, 0.f, 0.f};

    // prologue: chunk 0 -> buf 0
#pragma unroll
    for (int u = 0; u < 2; ++u)
        gload16(gbase[u], &xs[0][((cq * 2 + u) * 64 + lane) * 4]);
    __syncthreads();  // vmcnt(0) drain + barrier

    const int row = lane;
    const int rs = row & 7;
    int p = 0;
    for (int ch = 0; ch < 16; ++ch) {
        if (ch + 1 < 16) {
#pragma unroll
            for (int u = 0; u < 2; ++u)
                gload16(gbase[u] + (ch + 1) * 32, &xs[p ^ 1][((cq * 2 + u) * 64 + lane) * 4]);
        }
        const float* xr = &xs[p][row * 32];
#pragma unroll
        for (int j = 0; j < 8; ++j) {
            int j4 = (j + cq * 2) & 7;            // per-wave rotation (bank spread)
            float4 xv = *(const float4*)(xr + ((j4 ^ rs) << 2));
            float xe[4] = {xv.x, xv.y, xv.z, xv.w};
            int k = ch * 32 + j4 * 4;
#pragma unroll
            for (int d = 0; d < 4; ++d) {
                const float* wp = W1 + (k + d) * 16 + cq * 4;  // wave-uniform -> s_load
#pragma unroll
                for (int c = 0; c < 4; ++c) acc[c] = fmaf(xe[d], wp[c], acc[c]);
            }
        }
        __syncthreads();  // prefetch of ch+1 stays in flight across this
        p ^= 1;
    }

    int orow = R0 + row;
    if (orow < N) {
        float di = dinv[orow];
        *(float4*)(h1 + (size_t)orow * 16 + cq * 4) =
            make_float4(acc[0] * di, acc[1] * di, acc[2] * di, acc[3] * di);
    }
}

// ---------------- Aggregation layer 1: relu1 = relu(di * sum(h1') + b1) ----------------

__global__ void k_gather1(const float* __restrict__ h1, const int* __restrict__ csr_src,
                          const int* __restrict__ rowStart, const int* __restrict__ hist,
                          const float* __restrict__ dinv, const float* __restrict__ b1,
                          int N, float* __restrict__ relu1) {
    int g = blockIdx.x * blockDim.x + threadIdx.x;
    int i = g >> 4, c = g & 15;
    if (i >= N) return;
    float ssum = h1[(size_t)i * 16 + c];  // self-loop (already * dinv[i])
    int e0 = rowStart[i], e1 = e0 + hist[i];
    for (int e = e0; e < e1; ++e) {
        int s = csr_src[e];
        ssum += h1[(size_t)s * 16 + c];
    }
    float v = fmaf(dinv[i], ssum, b1[c]);
    relu1[(size_t)i * 16 + c] = fmaxf(v, 0.0f);
}

// ---------------- h2 = (relu1 @ W2) * dinv[i]  (W2 [16,7]) ----------------

__global__ void k_h2(const float* __restrict__ relu1, const float* __restrict__ W2,
                     const float* __restrict__ dinv, int N, float* __restrict__ h2) {
    int i = blockIdx.x * blockDim.x + threadIdx.x;
    if (i >= N) return;
    float r[16];
#pragma unroll
    for (int q = 0; q < 4; ++q) {
        float4 v = *(const float4*)(relu1 + (size_t)i * 16 + q * 4);
        r[q * 4 + 0] = v.x; r[q * 4 + 1] = v.y; r[q * 4 + 2] = v.z; r[q * 4 + 3] = v.w;
    }
    float di = dinv[i];
#pragma unroll
    for (int c2 = 0; c2 < 7; ++c2) {
        float a = 0.0f;
#pragma unroll
        for (int c = 0; c < 16; ++c) a = fmaf(r[c], W2[c * 7 + c2], a);
        h2[(size_t)i * 7 + c2] = a * di;
    }
}

// ---------------- Aggregation layer 2: out = di * sum(h2') + b2 ----------------

__global__ void k_gather2(const float* __restrict__ h2, const int* __restrict__ csr_src,
                          const int* __restrict__ rowStart, const int* __restrict__ hist,
                          const float* __restrict__ dinv, const float* __restrict__ b2,
                          int N, float* __restrict__ out) {
    int g = blockIdx.x * blockDim.x + threadIdx.x;
    int i = g >> 3, c = g & 7;
    if (i >= N || c >= 7) return;
    float ssum = h2[(size_t)i * 7 + c];
    int e0 = rowStart[i], e1 = e0 + hist[i];
    for (int e = e0; e < e1; ++e) {
        int s = csr_src[e];
        ssum += h2[(size_t)s * 7 + c];
    }
    out[(size_t)i * 7 + c] = fmaf(dinv[i], ssum, b2[c]);
}

// ---------------- launch ----------------

extern "C" void kernel_launch(void* const* d_in, const int* in_sizes, int n_in,
                              void* d_out, int out_size, void* d_ws, size_t ws_size,
                              hipStream_t stream) {
    const float* x  = (const float*)d_in[0];
    const int*   ei = (const int*)d_in[1];
    const float* W1 = (const float*)d_in[2];
    const float* b1 = (const float*)d_in[3];
    const float* W2 = (const float*)d_in[4];
    const float* b2 = (const float*)d_in[5];
    float* out = (float*)d_out;

    const int N = in_sizes[0] / 512;
    const int E = in_sizes[1] / 2;
    const int* src = ei;       // edge_index[0]
    const int* dst = ei + E;   // edge_index[1]

    const int nb  = (N + 255) / 256;           // 391 node blocks == coarse buckets
    const int B   = nb;
    const int nbA = (E + CHUNK - 1) / CHUNK;   // 391 coarse blocks
    const int nb64 = (N + 63) / 64;            // 1563 gemm row-blocks (64 rows each)

    char* ws = (char*)d_ws;
    auto alloc = [&](size_t bytes) {
        char* p = ws;
        ws += (bytes + 511) & ~(size_t)511;
        return p;
    };
    // persistent region
    int*   hist      = (int*)alloc((size_t)N * 4);
    float* dinv      = (float*)alloc((size_t)N * 4);
    int*   rowStart  = (int*)alloc((size_t)N * 4);
    int*   bc        = (int*)alloc((size_t)(B + 1) * 4);
    int*   blockBase = (int*)alloc((size_t)nbA * B * 4);
    int*   csr_src   = (int*)alloc((size_t)E * 4);
    // overlapped region: ebuf (dead after fine_scatter) unions with h1/relu1/h2
    size_t featBytes = (size_t)N * 16 * 4 * 2 + (size_t)N * 7 * 4;
    size_t ebufBytes = (size_t)E * 4;
    char* regB = alloc(featBytes > ebufBytes ? featBytes : ebufBytes);
    unsigned int* ebuf = (unsigned int*)regB;
    float* h1    = (float*)regB;
    float* relu1 = h1 + (size_t)N * 16;
    float* h2    = relu1 + (size_t)N * 16;

    hipMemsetAsync(bc, 0, (size_t)B * 4, stream);
    k_coarse_hist<<<nbA, 256, 0, stream>>>(dst, E, bc, blockBase, B);
    k_scan_bsums<<<1, 512, 0, stream>>>(bc, B);                       // bc -> bucketBase
    k_coarse_scatter<<<nbA, 256, 0, stream>>>(src, dst, E, bc, blockBase, B, ebuf);
    k_bucket_hist<<<B, 256, 0, stream>>>(ebuf, bc, E, N, B, hist, dinv);
    k_fine_scatter<<<B, 256, 0, stream>>>(ebuf, bc, hist, E, N, B, rowStart, csr_src);
    k_gemm1<<<nb64, 256, 0, stream>>>(x, W1, dinv, N, h1);
    k_gather1<<<(N * 16 + 255) / 256, 256, 0, stream>>>(h1, csr_src, rowStart, hist, dinv, b1, N, relu1);
    k_h2<<<nb, 256, 0, stream>>>(relu1, W2, dinv, N, h2);
    k_gather2<<<(N * 8 + 255) / 256, 256, 0, stream>>>(h2, csr_src, rowStart, hist, dinv, b2, N, out);
}